// Round 1
// baseline (151.091 us; speedup 1.0000x reference)
//
#include <hip/hip_runtime.h>
#include <hip/hip_bf16.h>

#define NROWS 12288
#define DDIM  128
#define TILE  128
#define LDSS  136   // padded LDS row stride (elements): 272 B rows, 16B-aligned, conflict-free

typedef __bf16 bf16x8 __attribute__((ext_vector_type(8)));
typedef float  f32x4  __attribute__((ext_vector_type(4)));

__device__ __forceinline__ unsigned short f2bf(float f) {
    union { float f; unsigned u; } a; a.f = f;
    unsigned r = a.u + 0x7fffu + ((a.u >> 16) & 1u);   // RNE to bf16
    return (unsigned short)(r >> 16);
}

__global__ void convert_kernel(const float* __restrict__ x, unsigned short* __restrict__ xb) {
    int i = (blockIdx.x * 256 + threadIdx.x) * 4;
    float4 v = *(const float4*)(x + i);
    ushort4 o;
    o.x = f2bf(v.x); o.y = f2bf(v.y); o.z = f2bf(v.z); o.w = f2bf(v.w);
    *(ushort4*)(xb + i) = o;
}

// One block per upper-triangular 128x128 tile (bi <= bj).
// sim[i][j] = dot(x_i, x_j)/T; exp; row-sums -> rowsum[i], col-sums -> rowsum[j] (symmetry).
__global__ __launch_bounds__(256, 2) void gemm_exp_rowsum(
    const unsigned short* __restrict__ xb, float* __restrict__ rowsum)
{
    __shared__ unsigned short As[TILE * LDSS];
    __shared__ unsigned short Bs[TILE * LDSS];
    __shared__ float rsum[TILE];
    __shared__ float csum[TILE];

    const int bi = blockIdx.y, bj = blockIdx.x;
    if (bj < bi) return;                    // uniform whole-block exit, before any barrier
    const bool diag = (bi == bj);
    const int i0 = bi * TILE, j0 = bj * TILE;
    const int tid = threadIdx.x;

    if (tid < TILE) { rsum[tid] = 0.f; csum[tid] = 0.f; }

    // Stage A (rows i0..i0+127) and B (rows j0..j0+127), 16B per thread per iter.
    #pragma unroll
    for (int it = 0; it < 8; ++it) {
        int idx = it * 256 + tid;
        int r  = idx >> 4;
        int cg = idx & 15;
        *(uint4*)(&As[r * LDSS + cg * 8]) = *(const uint4*)(xb + (size_t)(i0 + r) * DDIM + cg * 8);
        *(uint4*)(&Bs[r * LDSS + cg * 8]) = *(const uint4*)(xb + (size_t)(j0 + r) * DDIM + cg * 8);
    }
    __syncthreads();

    const int wave = tid >> 6;
    const int wm = wave >> 1, wn = wave & 1;   // 2x2 waves, each 64x64
    const int lane = tid & 63;
    const int m16 = lane & 15, q = lane >> 4;

    f32x4 acc[4][4] = {};

    #pragma unroll
    for (int ks = 0; ks < 4; ++ks) {
        const int kk = ks * 32 + q * 8;
        bf16x8 af[4], bfr[4];
        #pragma unroll
        for (int mi = 0; mi < 4; ++mi)
            af[mi] = *(const bf16x8*)(&As[(wm * 64 + mi * 16 + m16) * LDSS + kk]);
        #pragma unroll
        for (int ni = 0; ni < 4; ++ni)
            bfr[ni] = *(const bf16x8*)(&Bs[(wn * 64 + ni * 16 + m16) * LDSS + kk]);
        #pragma unroll
        for (int mi = 0; mi < 4; ++mi)
            #pragma unroll
            for (int ni = 0; ni < 4; ++ni)
                acc[mi][ni] = __builtin_amdgcn_mfma_f32_16x16x32_bf16(af[mi], bfr[ni], acc[mi][ni], 0, 0, 0);
    }

    // C/D layout (16x16x32): col = lane&15, row = q*4 + reg  [m89-verified]
    // acc[mi][ni][r]: i = i0 + wm*64 + mi*16 + q*4 + r ; j = j0 + wn*64 + ni*16 + m16
    const float invT = 14.285714285714286f;
    float cp[4] = {0.f, 0.f, 0.f, 0.f};
    #pragma unroll
    for (int mi = 0; mi < 4; ++mi) {
        float rp[4] = {0.f, 0.f, 0.f, 0.f};
        #pragma unroll
        for (int ni = 0; ni < 4; ++ni) {
            #pragma unroll
            for (int r = 0; r < 4; ++r) {
                float ev = __expf(acc[mi][ni][r] * invT);
                rp[r]  += ev;
                cp[ni] += ev;
            }
        }
        #pragma unroll
        for (int r = 0; r < 4; ++r) {
            float s = rp[r];
            s += __shfl_xor(s, 1);
            s += __shfl_xor(s, 2);
            s += __shfl_xor(s, 4);
            s += __shfl_xor(s, 8);
            if (m16 == 0) atomicAdd(&rsum[wm * 64 + mi * 16 + q * 4 + r], s);
        }
    }
    if (!diag) {
        #pragma unroll
        for (int ni = 0; ni < 4; ++ni) {
            float s = cp[ni];
            s += __shfl_xor(s, 16);
            s += __shfl_xor(s, 32);
            if (q == 0) atomicAdd(&csum[wn * 64 + ni * 16 + m16], s);
        }
    }
    __syncthreads();

    if (tid < TILE) {
        atomicAdd(&rowsum[i0 + tid], rsum[tid]);
        if (!diag) atomicAdd(&rowsum[j0 + tid], csum[tid]);
    }
}

__global__ void finalize_kernel(const float* __restrict__ rowsum, float* __restrict__ out) {
    __shared__ float red[4];
    float acc = 0.f;
    for (int i = threadIdx.x; i < NROWS; i += 256)
        acc += __logf(rowsum[i]);
    #pragma unroll
    for (int off = 1; off < 64; off <<= 1)
        acc += __shfl_xor(acc, off);
    const int wave = threadIdx.x >> 6, lane = threadIdx.x & 63;
    if (lane == 0) red[wave] = acc;
    __syncthreads();
    if (threadIdx.x == 0)
        out[0] = (red[0] + red[1] + red[2] + red[3]) * (1.0f / (float)NROWS);
}

extern "C" void kernel_launch(void* const* d_in, const int* in_sizes, int n_in,
                              void* d_out, int out_size, void* d_ws, size_t ws_size,
                              hipStream_t stream) {
    const float* x = (const float*)d_in[0];
    float* out = (float*)d_out;

    float* rowsum = (float*)d_ws;                                    // 12288 floats (48 KB)
    unsigned short* xb = (unsigned short*)((char*)d_ws + NROWS * sizeof(float)); // 3 MB bf16

    hipMemsetAsync(rowsum, 0, NROWS * sizeof(float), stream);

    convert_kernel<<<dim3((NROWS * DDIM) / (4 * 256)), dim3(256), 0, stream>>>(x, xb);

    dim3 grid(NROWS / TILE, NROWS / TILE);   // 96x96, lower triangle exits immediately
    gemm_exp_rowsum<<<grid, dim3(256), 0, stream>>>(xb, rowsum);

    finalize_kernel<<<dim3(1), dim3(256), 0, stream>>>(rowsum, out);
}

// Round 2
// 105.861 us; speedup vs baseline: 1.4273x; 1.4273x over previous
//
#include <hip/hip_runtime.h>
#include <hip/hip_bf16.h>

#define NROWS 12288
#define DDIM  128
#define NT    96      // 12288/128 tiles per dimension
#define CHUNK 4       // j-tiles per block
#define NBLK  1200    // sum over bands of ceil((96-bi)/4)

typedef __bf16 bf16x8 __attribute__((ext_vector_type(8)));
typedef float  f32x4  __attribute__((ext_vector_type(4)));

// async global->LDS, 16B per lane; LDS dst is wave-uniform base + lane*16
#define GLD_LDS(g, l) __builtin_amdgcn_global_load_lds(                      \
    (const __attribute__((address_space(1))) void*)(g),                      \
    (__attribute__((address_space(3))) void*)(l), 16, 0, 0)

__device__ __forceinline__ unsigned short f2bf(float f) {
    union { float f; unsigned u; } a; a.f = f;
    unsigned r = a.u + 0x7fffu + ((a.u >> 16) & 1u);   // RNE to bf16
    return (unsigned short)(r >> 16);
}

__global__ void convert_kernel(const float* __restrict__ x, unsigned short* __restrict__ xb,
                               float* __restrict__ rowsum, float* __restrict__ out) {
    int gid = blockIdx.x * 256 + threadIdx.x;
    int i = gid * 4;
    float4 v = *(const float4*)(x + i);
    ushort4 o;
    o.x = f2bf(v.x); o.y = f2bf(v.y); o.z = f2bf(v.z); o.w = f2bf(v.w);
    *(ushort4*)(xb + i) = o;
    if (gid < NROWS) rowsum[gid] = 0.f;
    if (gid == 0) out[0] = 0.f;
}

// Stage one 128x128 bf16 tile into LDS via global_load_lds, XOR-swizzled:
// LDS slot (row, s) holds global 16B-chunk (s ^ (row&7)) of row.
__device__ __forceinline__ void stage_tile(const unsigned short* __restrict__ xb,
                                           int row0, unsigned short* lds,
                                           int wave, int lane) {
    #pragma unroll
    for (int it = 0; it < 8; ++it) {
        int rbase = wave * 32 + it * 4;               // wave-uniform
        int r = rbase + (lane >> 4);
        int chunk = (lane & 15) ^ (r & 7);
        GLD_LDS(xb + (size_t)(row0 + r) * DDIM + chunk * 8, lds + rbase * DDIM);
    }
}

// One block per chunk of up-to-4 upper-triangular 128x128 tiles sharing a row band.
// A-fragments register-resident across the strip; row partials in registers.
__global__ __launch_bounds__(256, 2) void gemm_exp_rowsum(
    const unsigned short* __restrict__ xb, float* __restrict__ rowsum)
{
    __shared__ __align__(16) unsigned short As[128 * DDIM];
    __shared__ __align__(16) unsigned short Bs[128 * DDIM];
    __shared__ float csumS[CHUNK * 128];
    __shared__ float rsum[128];

    const int tid = threadIdx.x;

    // decode blockIdx -> (band bi, chunk start jt0)
    int rem = blockIdx.x, bi = 0;
    for (;;) {
        int nch = (NT - bi + CHUNK - 1) / CHUNK;
        if (rem < nch) break;
        rem -= nch; ++bi;
    }
    const int jt0 = bi + rem * CHUNK;
    const int ntiles = min(CHUNK, NT - jt0);
    const int i0 = bi * 128;

    for (int k = tid; k < CHUNK * 128; k += 256) csumS[k] = 0.f;
    if (tid < 128) rsum[tid] = 0.f;

    const int wave = tid >> 6, lane = tid & 63;
    const int wm = wave >> 1, wn = wave & 1;      // 2x2 waves, 64x64 each
    const int m16 = lane & 15, q = lane >> 4;

    stage_tile(xb, i0, As, wave, lane);
    __syncthreads();   // DMA complete (vmcnt drained) + csum/rsum zeroed

    // A fragments: row = wm*64+mi*16+m16, k-chunk = ks*4+q (swizzled). Stay in VGPRs.
    bf16x8 af[4][4];
    #pragma unroll
    for (int mi = 0; mi < 4; ++mi) {
        int r = wm * 64 + mi * 16 + m16;
        #pragma unroll
        for (int ks = 0; ks < 4; ++ks)
            af[mi][ks] = *(const bf16x8*)(&As[r * DDIM + (((ks * 4 + q) ^ (r & 7)) * 8)]);
    }

    const float invT = 14.285714285714286f;
    float rp[4][4];
    #pragma unroll
    for (int mi = 0; mi < 4; ++mi)
        #pragma unroll
        for (int r = 0; r < 4; ++r) rp[mi][r] = 0.f;

    for (int t = 0; t < ntiles; ++t) {
        const int jt = jt0 + t;
        __syncthreads();                       // prev tile's Bs reads done
        stage_tile(xb, jt * 128, Bs, wave, lane);
        __syncthreads();                       // staging DMA complete

        f32x4 acc[4][4] = {};
        #pragma unroll
        for (int ks = 0; ks < 4; ++ks) {
            bf16x8 bfr[4];
            #pragma unroll
            for (int ni = 0; ni < 4; ++ni) {
                int r = wn * 64 + ni * 16 + m16;
                bfr[ni] = *(const bf16x8*)(&Bs[r * DDIM + (((ks * 4 + q) ^ (r & 7)) * 8)]);
            }
            #pragma unroll
            for (int mi = 0; mi < 4; ++mi)
                #pragma unroll
                for (int ni = 0; ni < 4; ++ni)
                    acc[mi][ni] = __builtin_amdgcn_mfma_f32_16x16x32_bf16(
                        af[mi][ks], bfr[ni], acc[mi][ni], 0, 0, 0);
        }

        // C/D: col = m16, row = q*4 + r  [verified round 1]
        float cp[4] = {0.f, 0.f, 0.f, 0.f};
        #pragma unroll
        for (int mi = 0; mi < 4; ++mi)
            #pragma unroll
            for (int ni = 0; ni < 4; ++ni)
                #pragma unroll
                for (int r = 0; r < 4; ++r) {
                    float ev = __expf(acc[mi][ni][r] * invT);
                    rp[mi][r] += ev;           // row partial (register, whole strip)
                    cp[ni] += ev;              // col partial (this tile)
                }

        if (jt != bi) {                        // diagonal tile: rows == cols, no double count
            #pragma unroll
            for (int ni = 0; ni < 4; ++ni) {
                float s = cp[ni];
                s += __shfl_xor(s, 16);
                s += __shfl_xor(s, 32);
                if (q == 0) atomicAdd(&csumS[t * 128 + wn * 64 + ni * 16 + m16], s);
            }
        }
    }

    // row reduction: once per block
    #pragma unroll
    for (int mi = 0; mi < 4; ++mi)
        #pragma unroll
        for (int r = 0; r < 4; ++r) {
            float s = rp[mi][r];
            s += __shfl_xor(s, 1);
            s += __shfl_xor(s, 2);
            s += __shfl_xor(s, 4);
            s += __shfl_xor(s, 8);
            if (m16 == 0) atomicAdd(&rsum[wm * 64 + mi * 16 + q * 4 + r], s);
        }
    __syncthreads();

    if (tid < 128) atomicAdd(&rowsum[i0 + tid], rsum[tid]);
    for (int k = tid; k < ntiles * 128; k += 256) {
        float v = csumS[k];
        if (v != 0.f) atomicAdd(&rowsum[jt0 * 128 + k], v);
    }
}

__global__ void finalize_kernel(const float* __restrict__ rowsum, float* __restrict__ out) {
    __shared__ float red[4];
    int gid = blockIdx.x * 256 + threadIdx.x;
    float lg = __logf(rowsum[gid]);
    #pragma unroll
    for (int off = 1; off < 64; off <<= 1)
        lg += __shfl_xor(lg, off);
    const int wv = threadIdx.x >> 6, ln = threadIdx.x & 63;
    if (ln == 0) red[wv] = lg;
    __syncthreads();
    if (threadIdx.x == 0)
        atomicAdd(out, (red[0] + red[1] + red[2] + red[3]) * (1.0f / (float)NROWS));
}

extern "C" void kernel_launch(void* const* d_in, const int* in_sizes, int n_in,
                              void* d_out, int out_size, void* d_ws, size_t ws_size,
                              hipStream_t stream) {
    const float* x = (const float*)d_in[0];
    float* out = (float*)d_out;

    float* rowsum = (float*)d_ws;                                                 // 48 KB
    unsigned short* xb = (unsigned short*)((char*)d_ws + NROWS * sizeof(float));  // 3 MB bf16

    convert_kernel<<<dim3((NROWS * DDIM) / (4 * 256)), dim3(256), 0, stream>>>(x, xb, rowsum, out);
    gemm_exp_rowsum<<<dim3(NBLK), dim3(256), 0, stream>>>(xb, rowsum);
    finalize_kernel<<<dim3(NROWS / 256), dim3(256), 0, stream>>>(rowsum, out);
}